// Round 14
// baseline (160.532 us; speedup 1.0000x reference)
//
#include <hip/hip_runtime.h>

#define I_DIM 17
#define H_DIM 128
#define T_DIM 19
#define B_DIM 32768
#define M_ROWS 64
#define NTHR 1024
#define GRID (B_DIM / M_ROWS) /* 512 blocks, 1/CU, 2 passes */
#define XI 323
#define XSLOT 2176            /* per-t x slot: 4 rowgrp x 512B (k0..15) + 128B k16 plane */

/* LDS map (bytes) */
#define OFF_WHH 0             /* 128 frags x 1024 = 131072 */
#define OFF_H   131072        /* [64][256B] single buffer = 16384 */
#define OFF_X   147456        /* 2 slots x 2176 = 4352 */
#define OFF_WO  151808        /* 8 frags x 1024 = 8192 */
#define LDS_TOT 160000

typedef __bf16 bf16x8 __attribute__((ext_vector_type(8)));
typedef float f32x4 __attribute__((ext_vector_type(4)));
typedef float f32x4u __attribute__((ext_vector_type(4), aligned(4)));
union FragU { bf16x8 v; unsigned short s[8]; uint4 u; };

#define K1 1.4426950408889634f
#define K2 2.8853900817779268f

__device__ __forceinline__ unsigned short f2bf(float f) {
    union { float f; unsigned u; } x; x.f = f;
    return (unsigned short)((x.u + 0x8000u) >> 16);
}

/* gates (transposed D): acc[tile][g]; bias arrives via k17 of x-proj */
#define STEP_READ(P_, REC_) do {                                                  \
    _Pragma("unroll") for (int tile = 0; tile < 2; ++tile) {                      \
        FragU fx; fx.u = (uint4){0u, 0u, 0u, 0u};                                 \
        if (q < 2)                                                                \
            fx.v = *(const bf16x8*)(smem + xyA + ((P_) * XSLOT + tile * 512));    \
        else if (q == 2) {                                                        \
            fx.s[0] = *(const unsigned short*)(smem + xk16 + ((P_) * XSLOT + tile * 32)); \
            fx.s[1] = (unsigned short)0x3F80;  /* 1.0 -> bias row */              \
        }                                                                         \
        _Pragma("unroll") for (int g = 0; g < 4; ++g) {                           \
            f32x4 z = {0.f, 0.f, 0.f, 0.f};                                       \
            acc[tile][g] = __builtin_amdgcn_mfma_f32_16x16x32_bf16(wihr[g], fx.v, z, 0, 0, 0); \
        }                                                                         \
    }                                                                             \
    if (REC_) {                                                                   \
        _Pragma("unroll") for (int kk = 0; kk < 4; ++kk) {                        \
            bf16x8 aw[4];                                                         \
            _Pragma("unroll") for (int g = 0; g < 4; ++g)                         \
                aw[g] = *(const bf16x8*)(smem + vwhh + (kk * 4096 + g * 1024));   \
            _Pragma("unroll") for (int tile = 0; tile < 2; ++tile) {              \
                bf16x8 hb = *(const bf16x8*)(smem + vkk[kk] + tile * 4096);       \
                _Pragma("unroll") for (int g = 0; g < 4; ++g)                     \
                    acc[tile][g] = __builtin_amdgcn_mfma_f32_16x16x32_bf16(aw[g], hb, acc[tile][g], 0, 0, 0); \
            }                                                                     \
        }                                                                         \
    }                                                                             \
} while (0)

/* elementwise + b64 h-write for one 16-row tile */
#define ELEM_T(TILE_) do {                                                        \
    unsigned long long hp = 0ull;                                                 \
    _Pragma("unroll") for (int r = 0; r < 4; ++r) {                               \
        float ui = __builtin_amdgcn_exp2f(acc[TILE_][0][r]);                      \
        float uf = __builtin_amdgcn_exp2f(acc[TILE_][1][r]);                      \
        float vg = __builtin_amdgcn_exp2f(acc[TILE_][2][r]);                      \
        float uo = __builtin_amdgcn_exp2f(acc[TILE_][3][r]);                      \
        float A_ = 1.f + ui, F_ = 1.f + uf, G_ = 1.f + vg;                        \
        float AG = A_ * G_;                                                       \
        int ci = (TILE_) * 4 + r;                                                 \
        float c = (cst[ci] * AG + (1.f - vg) * F_) * __builtin_amdgcn_rcpf(F_ * AG); \
        cst[ci] = c;                                                              \
        float vc = __builtin_amdgcn_exp2f(-K2 * c);                               \
        float h = (1.f - vc) * __builtin_amdgcn_rcpf((1.f + uo) * (1.f + vc));    \
        union { float f; unsigned u; } hu; hu.f = h;                              \
        hp |= (unsigned long long)((hu.u + 0x8000u) >> 16) << (16 * r);           \
    }                                                                             \
    *(unsigned long long*)(smem + vwrT + (TILE_) * 4096) = hp;                    \
} while (0)

/* y_{T-1}^T: waves 0..7, one 16-row x 16-col tile each */
#define Y_BURST() do {                                                            \
    if (w < 8) {                                                                  \
        f32x4 ya = {0.f, 0.f, 0.f, 0.f};                                          \
        _Pragma("unroll") for (int kk = 0; kk < 4; ++kk) {                        \
            bf16x8 wa = *(const bf16x8*)(smem + vwo + kk * 1024);                 \
            bf16x8 hb = *(const bf16x8*)(smem + yv[kk]);                          \
            ya = __builtin_amdgcn_mfma_f32_16x16x32_bf16(wa, hb, ya, 0, 0, 0);    \
        }                                                                         \
        if (yct == 0) {                                                           \
            *(f32x4u*)ypt = ya + ybo;                                             \
        } else if (q == 0) {                                                      \
            ypt[0] = ya[0] + ybo[0];                                              \
        }                                                                         \
        ypt += I_DIM;                                                             \
    }                                                                             \
} while (0)

/* one timestep: reads H (t-1) + x slot P; writes H (t) + x slot 1-P */
#define STEP(T_, P_, REC_) do {                                                   \
    float xr1 = 0.f, xr2 = 0.f;                                                   \
    const bool pf = (T_) + 1 < T_DIM;                                             \
    if (pf) { xr1 = xp1[17]; if (xv2) xr2 = xp2[17]; }                            \
    xp1 += 17; xp2 += 17;                                                         \
    STEP_READ(P_, REC_);                                                          \
    if (REC_) { Y_BURST(); __syncthreads(); }  /* A: H reads done */              \
    ELEM_T(0); ELEM_T(1);                                                         \
    if (pf) {                                                                     \
        *(unsigned short*)(smem + xd1 + (1 - (P_)) * XSLOT) = f2bf(xr1);          \
        if (xv2) *(unsigned short*)(smem + xd2 + (1 - (P_)) * XSLOT) = f2bf(xr2); \
    }                                                                             \
    __syncthreads();                           /* B: H + next x slot ready */     \
} while (0)

__global__ __launch_bounds__(NTHR)
__attribute__((amdgpu_waves_per_eu(4, 4)))
void flowlstm(
    const float* __restrict__ x, const float* __restrict__ W_ih,
    const float* __restrict__ W_hh, const float* __restrict__ b_ih,
    const float* __restrict__ b_hh, const float* __restrict__ W_out,
    const float* __restrict__ b_out, float* __restrict__ out)
{
    __shared__ __align__(16) unsigned char smem[LDS_TOT];
    const int tid = threadIdx.x;
    const int w = tid >> 6, lane = tid & 63, l15 = lane & 15, q = lane >> 4;
    const int mh = w >> 3, cg = w & 7;     /* wave: rows mh*32..+31, gate-cols g*128+cg*16+4q+r */
    const int b0 = blockIdx.x * M_ROWS;

    /* ---- stage W_hh -> LDS frags, PRE-SCALED (128 frags = cg*16+kk*4+g) ---- */
    #pragma unroll
    for (int i = 0; i < 8; ++i) {
        int s = tid + i * NTHR;           /* 0..8191 */
        int ln = s & 63, f = s >> 6;
        int g = f & 3, kk = (f >> 2) & 3, cgs = f >> 4;
        float sc = (g == 2) ? -K2 : -K1;
        int n = g * H_DIM + cgs * 16 + (ln & 15);
        const float* sp = W_hh + n * H_DIM + kk * 32 + (ln >> 4) * 8;
        FragU fu;
        #pragma unroll
        for (int e = 0; e < 8; ++e) fu.s[e] = f2bf(sp[e] * sc);
        *(uint4*)(smem + OFF_WHH + f * 1024 + ln * 16) = fu.u;
    }
    /* ---- W_out fragments -> LDS (8 frags = ct*4+kk, N pad 17->32) ---- */
    if (tid < 512) {
        int ln = tid & 63, f = tid >> 6;
        int kk = f & 3, ct = f >> 2;
        int o = ct * 16 + (ln & 15);
        int kb = kk * 32 + (ln >> 4) * 8;
        FragU fu;
        #pragma unroll
        for (int e = 0; e < 8; ++e)
            fu.s[e] = (o < I_DIM) ? f2bf(W_out[o * H_DIM + kb + e]) : (unsigned short)0;
        *(uint4*)(smem + OFF_WO + f * 1024 + ln * 16) = fu.u;
    }
    /* ---- W_ih fragments in regs, PRE-SCALED, bias folded at k=17 ---- */
    bf16x8 wihr[4];
    #pragma unroll
    for (int g = 0; g < 4; ++g) {
        float sc = (g == 2) ? -K2 : -K1;
        int n = g * H_DIM + cg * 16 + l15;
        FragU fu;
        #pragma unroll
        for (int e = 0; e < 8; ++e) {
            int k = q * 8 + e;
            float v = 0.f;
            if (k < I_DIM)       v = W_ih[n * I_DIM + k] * sc;
            else if (k == I_DIM) v = (b_ih[n] + b_hh[n]) * sc;   /* bias row */
            fu.s[e] = f2bf(v);
        }
        wihr[g] = fu.v;
    }
    /* ---- t-invariant LDS vaddrs ---- */
    const unsigned xr7 = (unsigned)((l15 & 7) << 4);
    unsigned vkk[4], yv[4];
    #pragma unroll
    for (int kk = 0; kk < 4; ++kk)
        vkk[kk] = (unsigned)(OFF_H + mh * 8192 + l15 * 256 + ((kk * 64 + q * 16) ^ xr7));
    const unsigned vwrT = (unsigned)(OFF_H + mh * 8192 + l15 * 256 + (((cg * 16 + 4 * q) * 2) ^ xr7));
    const unsigned vwhh = (unsigned)(OFF_WHH + cg * 16384 + lane * 16);
    const int yct = w & 1;
    const unsigned ytile = (unsigned)((w >> 1) * 4096);
    #pragma unroll
    for (int kk = 0; kk < 4; ++kk)
        yv[kk] = (unsigned)(OFF_H + ytile + l15 * 256 + ((kk * 64 + q * 16) ^ xr7));
    const unsigned vwo = (unsigned)(OFF_WO + yct * 4096 + lane * 16);
    f32x4 ybo;
    #pragma unroll
    for (int r = 0; r < 4; ++r) {
        int col = yct * 16 + 4 * q + r;
        ybo[r] = b_out[col < I_DIM ? col : 16];
    }
    const unsigned xyA  = (unsigned)(OFF_X + mh * 1024 + (q < 2 ? q * 256 : 0) + l15 * 16);
    const unsigned xk16 = (unsigned)(OFF_X + 2048 + mh * 64 + l15 * 2);
    float* ypt = out + (size_t)(b0 + (w >> 1) * 16 + l15) * XI + (yct ? 16 : 4 * q);

    /* ---- x element mapping: f1 = tid (always valid), f2 = tid+1024 (tid<64) ---- */
    const unsigned row1 = ((unsigned)tid * 61681u) >> 20;          /* /17 */
    const unsigned k1 = (unsigned)tid - row1 * 17u;
    const bool xv2 = tid < (M_ROWS * I_DIM - NTHR);                /* tid < 64 */
    const unsigned f2v = (unsigned)(tid + NTHR);
    const unsigned row2 = xv2 ? ((f2v * 61681u) >> 20) : 0u;
    const unsigned k2 = xv2 ? (f2v - row2 * 17u) : 0u;
    const unsigned xd1 = (k1 == 16) ? (unsigned)(OFF_X + 2048 + row1 * 2)
        : (unsigned)(OFF_X + (row1 >> 4) * 512 + (k1 >> 3) * 256 + (row1 & 15) * 16 + (k1 & 7) * 2);
    const unsigned xd2 = (k2 == 16) ? (unsigned)(OFF_X + 2048 + row2 * 2)
        : (unsigned)(OFF_X + (row2 >> 4) * 512 + (k2 >> 3) * 256 + (row2 & 15) * 16 + (k2 & 7) * 2);
    const float* xp1 = x + (size_t)(b0 + row1) * XI + k1;
    const float* xp2 = x + (size_t)(b0 + row2) * XI + k2;

    /* ---- prologue: stage x slot 0 (t=0) ---- */
    *(unsigned short*)(smem + xd1) = f2bf(xp1[0]);
    if (xv2) *(unsigned short*)(smem + xd2) = f2bf(xp2[0]);

    float cst[8];
    #pragma unroll
    for (int i = 0; i < 8; ++i) cst[i] = 0.f;

    f32x4 acc[2][4];

    __syncthreads();   /* all staging visible */

    /* ---- t=0 peel (no recurrence, no y, no A-barrier) ---- */
    STEP(0, 0, 0);

    /* ---- t = 1..18 ---- */
    #pragma unroll 1
    for (int t = 1; t < T_DIM; t += 2) {
        STEP(t, 1, 1);
        STEP(t + 1, 0, 1);
    }

    /* ---- epilogue: y_18 from H ---- */
    if (w < 8) {
        f32x4 ya = {0.f, 0.f, 0.f, 0.f};
        #pragma unroll
        for (int kk = 0; kk < 4; ++kk) {
            bf16x8 wa = *(const bf16x8*)(smem + vwo + kk * 1024);
            bf16x8 hb = *(const bf16x8*)(smem + yv[kk]);
            ya = __builtin_amdgcn_mfma_f32_16x16x32_bf16(wa, hb, ya, 0, 0, 0);
        }
        if (yct == 0) {
            *(f32x4u*)ypt = ya + ybo;
        } else if (q == 0) {
            ypt[0] = ya[0] + ybo[0];
        }
    }
}

extern "C" void kernel_launch(void* const* d_in, const int* in_sizes, int n_in,
                              void* d_out, int out_size, void* d_ws, size_t ws_size,
                              hipStream_t stream) {
    const float* x     = (const float*)d_in[0];
    const float* W_ih  = (const float*)d_in[1];
    const float* W_hh  = (const float*)d_in[2];
    const float* b_ih  = (const float*)d_in[3];
    const float* b_hh  = (const float*)d_in[4];
    const float* W_out = (const float*)d_in[5];
    const float* b_out = (const float*)d_in[6];
    float* out = (float*)d_out;

    dim3 grid(GRID), block(NTHR);
    flowlstm<<<grid, block, 0, stream>>>(x, W_ih, W_hh, b_ih, b_hh, W_out, b_out, out);
}